// Round 1
// baseline (117304.114 us; speedup 1.0000x reference)
//
#include <hip/hip_runtime.h>
#include <cstdint>
#include <cstddef>

#define B_ 64
#define T_ 1024
#define D_ 1024

typedef __attribute__((ext_vector_type(8))) short short8;
typedef __attribute__((ext_vector_type(4))) float f32x4;
typedef unsigned short u16;

static __device__ __forceinline__ f32x4 mfma16(short8 a, short8 b, f32x4 c) {
  return __builtin_amdgcn_mfma_f32_16x16x32_bf16(a, b, c, 0, 0, 0);
}

static __device__ __forceinline__ short8 ld8(const u16* p) {
  return *reinterpret_cast<const short8*>(p);
}

static __device__ __forceinline__ u16 bf_of_f32(float f) {
  __bf16 h = (__bf16)f;
  return __builtin_bit_cast(u16, h);
}
static __device__ __forceinline__ float f32_of_bf(u16 b) {
  return (float)__builtin_bit_cast(__bf16, b);
}

// ---- GEMM pass helpers -------------------------------------------------
// Wave layout: wave = (kg 0..3) x (gate g 0..3); each wave computes 4 m-tiles
// (rows mi*16 + lane&15) x 1 n-tile (W rows wrowbase + lane&15), K-quarter kg.
// A-frag (16x16x32 bf16): lane l holds A[l&15][(l>>4)*8 + i], i=0..7.
// B-frag: lane l holds B[(l>>4)*8+i][l&15] = W[l&15-th row][(l>>4)*8+i].

static __device__ __forceinline__ void pass_bf16(
    f32x4* acc, const u16* __restrict__ abase, size_t arowstride,
    const u16* __restrict__ Whi, const u16* __restrict__ Wlo,
    int wrowbase, int kg, int lane)
{
  const int kl = (lane >> 4) << 3;
  const int r = lane & 15;
  const u16* wh = Whi + (size_t)(wrowbase + r) * D_;
  const u16* wl = Wlo + (size_t)(wrowbase + r) * D_;
  #pragma unroll
  for (int ks = 0; ks < 8; ++ks) {
    const int k = kg * 256 + ks * 32 + kl;
    short8 bh = ld8(wh + k);
    short8 bl = ld8(wl + k);
    #pragma unroll
    for (int mi = 0; mi < 4; ++mi) {
      short8 a = ld8(abase + (size_t)(mi * 16 + r) * arowstride + k);
      acc[mi] = mfma16(a, bh, acc[mi]);
      acc[mi] = mfma16(a, bl, acc[mi]);
    }
  }
}

static __device__ __forceinline__ void pass_xpre(
    f32x4* acc, const u16* __restrict__ xh, const u16* __restrict__ xl,
    size_t arowstride, const u16* __restrict__ Whi, const u16* __restrict__ Wlo,
    int wrowbase, int kg, int lane)
{
  const int kl = (lane >> 4) << 3;
  const int r = lane & 15;
  const u16* wh = Whi + (size_t)(wrowbase + r) * D_;
  const u16* wl = Wlo + (size_t)(wrowbase + r) * D_;
  #pragma unroll
  for (int ks = 0; ks < 8; ++ks) {
    const int k = kg * 256 + ks * 32 + kl;
    short8 bh = ld8(wh + k);
    short8 bl = ld8(wl + k);
    #pragma unroll
    for (int mi = 0; mi < 4; ++mi) {
      const size_t ro = (size_t)(mi * 16 + r) * arowstride + k;
      short8 ah = ld8(xh + ro);
      short8 al = ld8(xl + ro);
      acc[mi] = mfma16(ah, bh, acc[mi]);
      acc[mi] = mfma16(al, bh, acc[mi]);   // x_lo * W_hi
      acc[mi] = mfma16(ah, bl, acc[mi]);   // x_hi * W_lo  (lo*lo negligible)
    }
  }
}

static __device__ __forceinline__ void pass_xf32(
    f32x4* acc, const float* __restrict__ xbase, size_t arowstride,
    const u16* __restrict__ Whi, const u16* __restrict__ Wlo,
    int wrowbase, int kg, int lane)
{
  const int kl = (lane >> 4) << 3;
  const int r = lane & 15;
  const u16* wh = Whi + (size_t)(wrowbase + r) * D_;
  const u16* wl = Wlo + (size_t)(wrowbase + r) * D_;
  #pragma unroll
  for (int ks = 0; ks < 8; ++ks) {
    const int k = kg * 256 + ks * 32 + kl;
    short8 bh = ld8(wh + k);
    short8 bl = ld8(wl + k);
    #pragma unroll
    for (int mi = 0; mi < 4; ++mi) {
      const float* xp = xbase + (size_t)(mi * 16 + r) * arowstride + k;
      short8 ah, al;
      #pragma unroll
      for (int e = 0; e < 8; ++e) {
        float f = xp[e];
        u16 hb = bf_of_f32(f);
        float rr = f - f32_of_bf(hb);
        ah[e] = (short)hb;
        al[e] = (short)bf_of_f32(rr);
      }
      acc[mi] = mfma16(ah, bh, acc[mi]);
      acc[mi] = mfma16(al, bh, acc[mi]);
      acc[mi] = mfma16(ah, bl, acc[mi]);
    }
  }
}

// ---- layer kernels -----------------------------------------------------
// grid 64 blocks (16 hidden dims each), 1024 threads (16 waves = 4 kg x 4 gates)

template <bool XPRE>
__global__ __launch_bounds__(1024) void lstm_l0(
    const float* __restrict__ x, const u16* __restrict__ xh, const u16* __restrict__ xl,
    const u16* __restrict__ Wih_hi, const u16* __restrict__ Wih_lo,
    const u16* __restrict__ Whh_hi, const u16* __restrict__ Whh_lo,
    const u16* __restrict__ hprev, u16* __restrict__ hcur,
    float* __restrict__ c, int t)
{
  __shared__ float gl[4][4][64][17];
  const int tid = threadIdx.x;
  const int lane = tid & 63;
  const int wv = tid >> 6;
  const int kg = wv >> 2;
  const int g = wv & 3;
  const int d0 = blockIdx.x << 4;
  const int wrowbase = g * D_ + d0;

  f32x4 acc[4];
  #pragma unroll
  for (int mi = 0; mi < 4; ++mi) acc[mi] = (f32x4){0.f, 0.f, 0.f, 0.f};

  if (XPRE)
    pass_xpre(acc, xh + (size_t)t * D_, xl + (size_t)t * D_, (size_t)T_ * D_,
              Wih_hi, Wih_lo, wrowbase, kg, lane);
  else
    pass_xf32(acc, x + (size_t)t * D_, (size_t)T_ * D_,
              Wih_hi, Wih_lo, wrowbase, kg, lane);
  pass_bf16(acc, hprev, D_, Whh_hi, Whh_lo, wrowbase, kg, lane);

  // D-frag: lane holds rows (lane>>4)*4+i, col lane&15 of each 16x16 tile
  const int r4 = (lane >> 4) << 2;
  const int dc = lane & 15;
  #pragma unroll
  for (int mi = 0; mi < 4; ++mi)
    #pragma unroll
    for (int i = 0; i < 4; ++i)
      gl[kg][g][mi * 16 + r4 + i][dc] = acc[mi][i];
  __syncthreads();

  {
    const int b = tid >> 4;
    const int dd = tid & 15;
    float gi = gl[0][0][b][dd] + gl[1][0][b][dd] + gl[2][0][b][dd] + gl[3][0][b][dd];
    float gf = gl[0][1][b][dd] + gl[1][1][b][dd] + gl[2][1][b][dd] + gl[3][1][b][dd];
    float gg = gl[0][2][b][dd] + gl[1][2][b][dd] + gl[2][2][b][dd] + gl[3][2][b][dd];
    float go = gl[0][3][b][dd] + gl[1][3][b][dd] + gl[2][3][b][dd] + gl[3][3][b][dd];
    float ii = 1.f / (1.f + expf(-gi));
    float ff = 1.f / (1.f + expf(-gf));
    float gt = tanhf(gg);
    float oo = 1.f / (1.f + expf(-go));
    const size_t ci = (size_t)b * D_ + d0 + dd;
    float cn = ff * c[ci] + ii * gt;
    c[ci] = cn;
    float hn = oo * tanhf(cn);
    hcur[ci] = bf_of_f32(hn);
  }
}

__global__ __launch_bounds__(1024) void lstm_l1(
    const u16* __restrict__ h0, const u16* __restrict__ h1prev,
    const u16* __restrict__ Wih_hi, const u16* __restrict__ Wih_lo,
    const u16* __restrict__ Whh_hi, const u16* __restrict__ Whh_lo,
    u16* __restrict__ h1cur, float* __restrict__ c,
    float* __restrict__ out, int t)
{
  __shared__ float gl[4][4][64][17];
  const int tid = threadIdx.x;
  const int lane = tid & 63;
  const int wv = tid >> 6;
  const int kg = wv >> 2;
  const int g = wv & 3;
  const int d0 = blockIdx.x << 4;
  const int wrowbase = g * D_ + d0;

  f32x4 acc[4];
  #pragma unroll
  for (int mi = 0; mi < 4; ++mi) acc[mi] = (f32x4){0.f, 0.f, 0.f, 0.f};

  pass_bf16(acc, h0, D_, Wih_hi, Wih_lo, wrowbase, kg, lane);
  pass_bf16(acc, h1prev, D_, Whh_hi, Whh_lo, wrowbase, kg, lane);

  const int r4 = (lane >> 4) << 2;
  const int dc = lane & 15;
  #pragma unroll
  for (int mi = 0; mi < 4; ++mi)
    #pragma unroll
    for (int i = 0; i < 4; ++i)
      gl[kg][g][mi * 16 + r4 + i][dc] = acc[mi][i];
  __syncthreads();

  {
    const int b = tid >> 4;
    const int dd = tid & 15;
    float gi = gl[0][0][b][dd] + gl[1][0][b][dd] + gl[2][0][b][dd] + gl[3][0][b][dd];
    float gf = gl[0][1][b][dd] + gl[1][1][b][dd] + gl[2][1][b][dd] + gl[3][1][b][dd];
    float gg = gl[0][2][b][dd] + gl[1][2][b][dd] + gl[2][2][b][dd] + gl[3][2][b][dd];
    float go = gl[0][3][b][dd] + gl[1][3][b][dd] + gl[2][3][b][dd] + gl[3][3][b][dd];
    float ii = 1.f / (1.f + expf(-gi));
    float ff = 1.f / (1.f + expf(-gf));
    float gt = tanhf(gg);
    float oo = 1.f / (1.f + expf(-go));
    const size_t ci = (size_t)b * D_ + d0 + dd;
    float cn = ff * c[ci] + ii * gt;
    c[ci] = cn;
    float hn = oo * tanhf(cn);
    h1cur[ci] = bf_of_f32(hn);
    out[((size_t)b * T_ + t) * D_ + d0 + dd] = hn;
  }
}

// ---- setup kernels -----------------------------------------------------

__global__ void convw(const float* __restrict__ w0, const float* __restrict__ w1,
                      const float* __restrict__ w2, const float* __restrict__ w3,
                      u16* __restrict__ hi, u16* __restrict__ lo)
{
  const size_t n1 = (size_t)4 * D_ * D_;  // 4M elems per matrix
  const size_t n = 4 * n1;
  for (size_t i = (size_t)blockIdx.x * blockDim.x + threadIdx.x; i < n;
       i += (size_t)gridDim.x * blockDim.x) {
    const size_t m = i / n1;
    const size_t j = i - m * n1;
    const float* src = (m == 0) ? w0 : (m == 1) ? w1 : (m == 2) ? w2 : w3;
    float f = src[j];
    u16 h = bf_of_f32(f);
    float r = f - f32_of_bf(h);
    hi[i] = h;
    lo[i] = bf_of_f32(r);
  }
}

__global__ void convx(const float* __restrict__ x, u16* __restrict__ xh,
                      u16* __restrict__ xl)
{
  const size_t n = (size_t)B_ * T_ * D_;
  for (size_t i = (size_t)blockIdx.x * blockDim.x + threadIdx.x; i < n;
       i += (size_t)gridDim.x * blockDim.x) {
    float f = x[i];
    u16 h = bf_of_f32(f);
    float r = f - f32_of_bf(h);
    xh[i] = h;
    xl[i] = bf_of_f32(r);
  }
}

// ---- host --------------------------------------------------------------

extern "C" void kernel_launch(void* const* d_in, const int* in_sizes, int n_in,
                              void* d_out, int out_size, void* d_ws, size_t ws_size,
                              hipStream_t stream) {
  (void)in_sizes; (void)n_in; (void)out_size;
  const float* x = (const float*)d_in[0];
  const float* Wih0 = (const float*)d_in[1];
  const float* Whh0 = (const float*)d_in[2];
  const float* Wih1 = (const float*)d_in[3];
  const float* Whh1 = (const float*)d_in[4];
  float* out = (float*)d_out;

  char* ws = (char*)d_ws;
  const size_t MB = 1ull << 20;
  const size_t n1 = (size_t)4 * D_ * D_;       // 4M elems per weight matrix

  // ws layout: [0,32MB) W hi planes; [32,64MB) W lo planes; [64,65MB) states;
  //            [65MB,...) optional x hi/lo planes (128MB each)
  u16* Whi = (u16*)ws;
  u16* Wlo = (u16*)(ws + 32 * MB);
  char* st = ws + 64 * MB;
  u16* h0buf = (u16*)st;                        // 2 x [64][1024] bf16
  u16* h1buf = (u16*)(st + (1 << 18));
  float* c0 = (float*)(st + (2 << 18));
  float* c1 = (float*)(st + (3 << 18));
  const size_t xplane = (size_t)B_ * T_ * D_ * 2;   // 128MB
  u16* xh = (u16*)(ws + 65 * MB);
  u16* xl = (u16*)(ws + 65 * MB + xplane);
  const bool xpre = ws_size >= 65 * MB + 2 * xplane;

  hipMemsetAsync(st, 0, 1 << 20, stream);       // zero h0/h1 ping-pong + c0/c1
  convw<<<2048, 256, 0, stream>>>(Wih0, Whh0, Wih1, Whh1, Whi, Wlo);
  if (xpre) convx<<<4096, 256, 0, stream>>>(x, xh, xl);

  const size_t HS = (size_t)B_ * D_;
  for (int t = 0; t < T_; ++t) {
    const u16* h0p = h0buf + (size_t)((t + 1) & 1) * HS;
    u16* h0c = h0buf + (size_t)(t & 1) * HS;
    const u16* h1p = h1buf + (size_t)((t + 1) & 1) * HS;
    u16* h1c = h1buf + (size_t)(t & 1) * HS;
    if (xpre)
      lstm_l0<true><<<64, 1024, 0, stream>>>(x, xh, xl, Whi, Wlo,
          Whi + n1, Wlo + n1, h0p, h0c, c0, t);
    else
      lstm_l0<false><<<64, 1024, 0, stream>>>(x, xh, xl, Whi, Wlo,
          Whi + n1, Wlo + n1, h0p, h0c, c0, t);
    lstm_l1<<<64, 1024, 0, stream>>>(h0c, h1p, Whi + 2 * n1, Wlo + 2 * n1,
        Whi + 3 * n1, Wlo + 3 * n1, h1c, c1, out, t);
  }
}

// Round 2
// 92946.198 us; speedup vs baseline: 1.2621x; 1.2621x over previous
//
#include <hip/hip_runtime.h>
#include <cstdint>
#include <cstddef>

#define B_ 64
#define T_ 1024
#define D_ 1024
#define NBLK 256

typedef __attribute__((ext_vector_type(8))) _Float16 half8;
typedef __attribute__((ext_vector_type(4))) float f32x4;
typedef unsigned int u32;

static __device__ __forceinline__ f32x4 mfma16(half8 a, half8 b, f32x4 c) {
  return __builtin_amdgcn_mfma_f32_16x16x32_f16(a, b, c, 0, 0, 0);
}
static __device__ __forceinline__ half8 ld8h(const _Float16* p) {
  return *reinterpret_cast<const half8*>(p);
}

// grid-wide barrier: monotone counter, ord = barrier ordinal (1-based, same in
// every block). counter zeroed by hipMemsetAsync before each kernel launch.
static __device__ __forceinline__ void gridbar(u32* bar, u32 ord) {
  __syncthreads();
  if (threadIdx.x == 0) {
    __threadfence();
    __hip_atomic_fetch_add(bar, 1u, __ATOMIC_RELEASE, __HIP_MEMORY_SCOPE_AGENT);
    const u32 target = ord * NBLK;
    while (__hip_atomic_load(bar, __ATOMIC_ACQUIRE, __HIP_MEMORY_SCOPE_AGENT) < target)
      __builtin_amdgcn_s_sleep(8);
    __threadfence();
  }
  __syncthreads();
}

__global__ void convw(const float* __restrict__ w0, const float* __restrict__ w1,
                      const float* __restrict__ w2, const float* __restrict__ w3,
                      _Float16* __restrict__ dst) {
  const size_t n1 = (size_t)4 * D_ * D_;
  const size_t n = 4 * n1;
  for (size_t i = (size_t)blockIdx.x * blockDim.x + threadIdx.x; i < n;
       i += (size_t)gridDim.x * blockDim.x) {
    const size_t m = i / n1, j = i - m * n1;
    const float* src = (m == 0) ? w0 : (m == 1) ? w1 : (m == 2) ? w2 : w3;
    dst[i] = (_Float16)src[j];
  }
}

// 256 blocks x 1024 threads, persistent. block = (lyr, kg, d-group).
// 16 waves = (kq 0..3) x (gate 0..3). wave: 4 m-tiles x 16 cols x K=128/GEMM.
// Super-step s: layer0 computes t=s (s<T), layer1 computes t=s-1 (s>=1).
__global__ __launch_bounds__(1024, 1) void lstm_persist(
    const float* __restrict__ x, const _Float16* __restrict__ W,
    _Float16* h0, _Float16* h1, float* c0, float* c1,
    float* gatesP, float* out, u32* bar)
{
  __shared__ float gl[4][4][64][17];
  const int tid = threadIdx.x;
  const int lane = tid & 63;
  const int wv = tid >> 6;
  const int kq = wv >> 2;
  const int g = wv & 3;
  const int bid = blockIdx.x;
  const int lyr = bid >> 7;
  const int kg = (bid >> 6) & 1;
  const int d0 = (bid & 63) << 4;

  const int r = lane & 15;          // A-row (batch) / B-row (W row) within tile
  const int kl = (lane >> 4) << 3;  // k sub-offset within 32-wide k-tile
  const int kbase = kg * 512 + kq * 128 + kl;

  const _Float16* Wih = W + (size_t)(2 * lyr) * 4096 * 1024
                          + (size_t)(g * 1024 + d0 + r) * 1024 + kbase;
  const _Float16* Whh = Wih + (size_t)4096 * 1024;
  const _Float16* hR = lyr ? h1 : h0;   // recurrent A input
  float* cc = lyr ? c1 : c0;
  _Float16* hh = lyr ? h1 : h0;

  u32 ord = 0;
  for (int s = 0; s <= T_; ++s) {
    const bool active = lyr ? (s >= 1) : (s < T_);
    const int t = lyr ? (s - 1) : s;

    if (active) {
      f32x4 acc[4];
      #pragma unroll
      for (int mi = 0; mi < 4; ++mi) acc[mi] = (f32x4){0.f, 0.f, 0.f, 0.f};

      if (lyr == 0) {
        // A = x[:, t, :] (f32, convert inline)
        const float* xb = x + (size_t)t * D_ + kbase;
        #pragma unroll
        for (int ksub = 0; ksub < 4; ++ksub) {
          half8 bf = ld8h(Wih + ksub * 32);
          #pragma unroll
          for (int mi = 0; mi < 4; ++mi) {
            const float* xp = xb + (size_t)(mi * 16 + r) * ((size_t)T_ * D_) + ksub * 32;
            half8 a;
            #pragma unroll
            for (int e = 0; e < 8; ++e) a[e] = (_Float16)xp[e];
            acc[mi] = mfma16(a, bf, acc[mi]);
          }
        }
      } else {
        // A = h0 (fp16)
        #pragma unroll
        for (int ksub = 0; ksub < 4; ++ksub) {
          half8 bf = ld8h(Wih + ksub * 32);
          #pragma unroll
          for (int mi = 0; mi < 4; ++mi) {
            half8 a = ld8h(h0 + (size_t)(mi * 16 + r) * D_ + kbase + ksub * 32);
            acc[mi] = mfma16(a, bf, acc[mi]);
          }
        }
      }
      // recurrent GEMM: A = hR
      #pragma unroll
      for (int ksub = 0; ksub < 4; ++ksub) {
        half8 bf = ld8h(Whh + ksub * 32);
        #pragma unroll
        for (int mi = 0; mi < 4; ++mi) {
          half8 a = ld8h(hR + (size_t)(mi * 16 + r) * D_ + kbase + ksub * 32);
          acc[mi] = mfma16(a, bf, acc[mi]);
        }
      }
      // C/D frag: col = lane&15, row = (lane>>4)*4 + i
      const int r4 = (lane >> 4) << 2;
      #pragma unroll
      for (int mi = 0; mi < 4; ++mi)
        #pragma unroll
        for (int i = 0; i < 4; ++i)
          gl[kq][g][mi * 16 + r4 + i][r] = acc[mi][i];
    }
    __syncthreads();
    if (active) {
      // reduce kq partials, write gate partials (per kg half) to global
      const int b = tid >> 4, dd = tid & 15;
      #pragma unroll
      for (int gg = 0; gg < 4; ++gg) {
        float v = gl[0][gg][b][dd] + gl[1][gg][b][dd]
                + gl[2][gg][b][dd] + gl[3][gg][b][dd];
        gatesP[(((size_t)(lyr * 2 + kg)) * 64 + b) * 4096 + gg * 1024 + d0 + dd] = v;
      }
    }

    gridbar(bar, ++ord);   // gates visible

    if (active && tid < 512) {
      // cell update: 128 blocks per layer x 512 cells = 64K (b,d) pairs
      const int ci = (bid & 127) * 512 + tid;
      const int b = ci >> 10, d = ci & 1023;
      const size_t p0 = (((size_t)(lyr * 2 + 0)) * 64 + b) * 4096 + d;
      const size_t p1 = (((size_t)(lyr * 2 + 1)) * 64 + b) * 4096 + d;
      const float gi = gatesP[p0] + gatesP[p1];
      const float gf = gatesP[p0 + 1024] + gatesP[p1 + 1024];
      const float gz = gatesP[p0 + 2048] + gatesP[p1 + 2048];
      const float go = gatesP[p0 + 3072] + gatesP[p1 + 3072];
      const float ii = 1.f / (1.f + expf(-gi));
      const float ff = 1.f / (1.f + expf(-gf));
      const float gt = tanhf(gz);
      const float oo = 1.f / (1.f + expf(-go));
      const size_t hi_ = (size_t)b * D_ + d;
      const float cn = ff * cc[hi_] + ii * gt;
      cc[hi_] = cn;
      const float hn = oo * tanhf(cn);
      hh[hi_] = (_Float16)hn;
      if (lyr) out[((size_t)b * T_ + t) * D_ + d] = hn;
    }

    gridbar(bar, ++ord);   // h/c visible before next super-step
  }
}

extern "C" void kernel_launch(void* const* d_in, const int* in_sizes, int n_in,
                              void* d_out, int out_size, void* d_ws, size_t ws_size,
                              hipStream_t stream) {
  (void)in_sizes; (void)n_in; (void)out_size; (void)ws_size;
  const float* x = (const float*)d_in[0];
  const float* Wih0 = (const float*)d_in[1];
  const float* Whh0 = (const float*)d_in[2];
  const float* Wih1 = (const float*)d_in[3];
  const float* Whh1 = (const float*)d_in[4];
  float* out = (float*)d_out;

  char* ws = (char*)d_ws;
  const size_t MB = 1ull << 20;
  // layout: [0,32MB) W fp16 (Wih0,Whh0,Wih1,Whh1); [32,36MB) gatesP f32;
  //         36MB: c0(256K) c1(256K) h0(128K) h1(128K) bar(4K)
  _Float16* Wf = (_Float16*)ws;
  float* gatesP = (float*)(ws + 32 * MB);
  float* c0 = (float*)(ws + 36 * MB);
  float* c1 = (float*)(ws + 36 * MB + 262144);
  _Float16* h0 = (_Float16*)(ws + 36 * MB + 2 * 262144);
  _Float16* h1 = (_Float16*)(ws + 36 * MB + 2 * 262144 + 131072);
  u32* bar = (u32*)(ws + 36 * MB + 2 * 262144 + 2 * 131072);

  // zero c0,c1,h0,h1,bar each call (deterministic, graph-safe)
  hipMemsetAsync(ws + 36 * MB, 0, 2 * 262144 + 2 * 131072 + 4096, stream);
  convw<<<2048, 256, 0, stream>>>(Wih0, Whh0, Wih1, Whh1, Wf);
  lstm_persist<<<NBLK, 1024, 0, stream>>>(x, Wf, h0, h1, c0, c1, gatesP, out, bar);
}

// Round 4
// 26876.315 us; speedup vs baseline: 4.3646x; 3.4583x over previous
//
#include <hip/hip_runtime.h>
#include <cstdint>
#include <cstddef>

#define B_ 64
#define T_ 1024
#define D_ 1024
#define NBLK 256

typedef __attribute__((ext_vector_type(8))) _Float16 half8;
typedef __attribute__((ext_vector_type(4))) float f32x4;
typedef unsigned int u32;
typedef unsigned long long u64;
typedef unsigned short u16;

static __device__ __forceinline__ f32x4 mfma16(half8 a, half8 b, f32x4 c) {
  return __builtin_amdgcn_mfma_f32_16x16x32_f16(a, b, c, 0, 0, 0);
}

// coherent (L2-bypass, sc1) ops — relaxed: NO buffer_inv / buffer_wbl2 emitted
static __device__ __forceinline__ u64 cohl64(const u64* p) {
  return __hip_atomic_load(p, __ATOMIC_RELAXED, __HIP_MEMORY_SCOPE_AGENT);
}
static __device__ __forceinline__ void cohs32(u32* p, u32 v) {
  __hip_atomic_store(p, v, __ATOMIC_RELAXED, __HIP_MEMORY_SCOPE_AGENT);
}

static __device__ __forceinline__ u16 h2u(_Float16 h) {
  return __builtin_bit_cast(u16, h);
}

// ---- staging: 32 rows x 1024 fp16 (64KB) into LDS, XOR-swizzled ----------
// thread t: row r = t>>5, chunk i = t&31 (64B = 32 fp16 at cols i*32..+32)

static __device__ __forceinline__ void stage_coh(
    const _Float16* src, size_t rstride, u64* reg, int tid) {
  const int r = tid >> 5, i = tid & 31;
  const u64* p = (const u64*)(src + (size_t)r * rstride + i * 32);
  #pragma unroll
  for (int j = 0; j < 8; ++j) reg[j] = cohl64(p + j);
}

static __device__ __forceinline__ void stage_nt(
    const _Float16* src, size_t rstride, u64* reg, int tid) {
  const int r = tid >> 5, i = tid & 31;
  const u64* p = (const u64*)(src + (size_t)r * rstride + i * 32);
  #pragma unroll
  for (int j = 0; j < 8; ++j) reg[j] = __builtin_nontemporal_load(p + j);
}

static __device__ __forceinline__ void stage_f32(
    const float* src, size_t rstride, u64* reg, int tid) {
  const int r = tid >> 5, i = tid & 31;
  const float4* p = (const float4*)(src + (size_t)r * rstride + i * 32);
  #pragma unroll
  for (int j = 0; j < 8; ++j) {
    float4 v = p[j];
    union { u16 us[4]; u64 u; } pk;
    pk.us[0] = h2u((_Float16)v.x); pk.us[1] = h2u((_Float16)v.y);
    pk.us[2] = h2u((_Float16)v.z); pk.us[3] = h2u((_Float16)v.w);
    reg[j] = pk.u;
  }
}

static __device__ __forceinline__ void stage_write(char* lds, const u64* reg, int tid) {
  const int r = tid >> 5, i = tid & 31;
  const int sw = (r & 7) << 4;
  #pragma unroll
  for (int u = 0; u < 4; ++u) {
    char* dst = lds + r * 2048 + (((i * 64) + u * 16) ^ sw);
    *(u64*)dst = reg[2 * u];
    *(u64*)(dst + 8) = reg[2 * u + 1];
  }
}

// ---- GEMM: wave = (kq, gate). Computes BOTH 16-row batch tiles sharing
// each weight fragment (1 b-load feeds 2 MFMAs). K quarter = 256 elems.
static __device__ __forceinline__ void gemm2(
    f32x4* acc, const char* ldsA, const _Float16* Wrow, int kq, int lane) {
  const int r = lane & 15;
  const int kl2 = (lane >> 4) << 4;      // byte offset of k-sublane
  const int sw = (r & 7) << 4;
  const int rb0 = r * 2048;
  const int rb1 = (16 + r) * 2048;       // (16+r)&7 == r&7 -> same swizzle
  #pragma unroll
  for (int ks = 0; ks < 8; ++ks) {
    const int kbyte = kq * 512 + ks * 64 + kl2;
    half8 b = *(const half8*)(Wrow + (kbyte >> 1));
    half8 a0 = *(const half8*)(ldsA + rb0 + (kbyte ^ sw));
    half8 a1 = *(const half8*)(ldsA + rb1 + (kbyte ^ sw));
    acc[0] = mfma16(a0, b, acc[0]);
    acc[1] = mfma16(a1, b, acc[1]);
  }
}

// ---- persistent kernel ---------------------------------------------------
// 256 blocks x 1024 threads. xcd = bid&7, slot = bid>>3:
//   lyr = slot>>4, mh = (slot>>3)&1, dgrp = xcd*8 + (slot&7)
// Both mh blocks of a (lyr,dgrp) share one XCD -> weight rows L2-resident once.
// block owns: layer lyr, batch rows mh*32..+32, dims d0..d0+16 (all 4 gates),
// full K=1024. 16 waves = (kq 0..3) x (gate 0..3), each wave does 2 m-tiles.
// Super-step s: lyr0 computes t=s (s<T), lyr1 computes t=s-1 (s>=1). 1 barrier.

template <bool XPRE>
__global__ __launch_bounds__(1024, 4) void lstm_persist(
    const float* __restrict__ x32, const _Float16* __restrict__ xh,
    const _Float16* __restrict__ W,
    _Float16* h0, _Float16* h1,    // [2 parity][B][D] each
    float* __restrict__ out, u32* bar)
{
  __shared__ char ldsA[32 * 2048];
  __shared__ float glp[4][32][68];
  const int tid = threadIdx.x;
  const int lane = tid & 63;
  const int wv = tid >> 6;
  const int kq = wv >> 2;
  const int nt = wv & 3;                   // gate index (i,f,g,o)
  const int bid = blockIdx.x;
  const int slot = bid >> 3;
  const int lyr = slot >> 4;
  const int mh = (slot >> 3) & 1;
  const int dgrp = (bid & 7) * 8 + (slot & 7);
  const int d0 = dgrp << 4;
  const int mbase = mh << 5;

  const _Float16* Wih = W + (size_t)(2 * lyr) * 4096 * 1024;
  const _Float16* Whh = Wih + (size_t)4096 * 1024;
  const size_t wrow = (size_t)(nt * 1024 + d0 + (lane & 15)) * 1024;
  const _Float16* WihR = Wih + wrow;
  const _Float16* WhhR = Whh + wrow;

  // cell registers: threads 0..255 each own 2 cells (batch cb, d = cd, cd+1)
  float creg0 = 0.f, creg1 = 0.f;
  const int cb = tid >> 3;
  const int cd = (tid & 7) << 1;

  const size_t HS = (size_t)B_ * D_;
  u64 ra[8], rb2[8];

  for (int s = 0; s <= T_; ++s) {
    const bool active = lyr ? (s >= 1) : (s < T_);
    const int t = lyr ? (s - 1) : s;
    const int pp = (s + 1) & 1, cc = s & 1;

    if (active) {
      const _Float16* h0p = h0 + (size_t)pp * HS + (size_t)mbase * D_;
      if (lyr == 0) {
        if (XPRE)
          stage_nt(xh + ((size_t)mbase * T_ + t) * D_, (size_t)T_ * D_, ra, tid);
        else
          stage_f32(x32 + ((size_t)mbase * T_ + t) * D_, (size_t)T_ * D_, ra, tid);
        stage_coh(h0p, D_, rb2, tid);          // recurrent input
      } else {
        stage_coh(h0p, D_, ra, tid);           // from layer 0
        stage_coh(h1 + (size_t)cc * HS + (size_t)mbase * D_, D_, rb2, tid);
      }

      f32x4 acc[2];
      acc[0] = (f32x4){0.f, 0.f, 0.f, 0.f};
      acc[1] = (f32x4){0.f, 0.f, 0.f, 0.f};
      stage_write(ldsA, ra, tid);
      __syncthreads();
      gemm2(acc, ldsA, WihR, kq, lane);
      __syncthreads();
      stage_write(ldsA, rb2, tid);
      __syncthreads();
      gemm2(acc, ldsA, WhhR, kq, lane);

      // write per-kq partials to LDS, reduce after sync
      const int r4 = (lane >> 4) << 2;
      const int ccol = nt * 16 + (lane & 15);
      #pragma unroll
      for (int mt = 0; mt < 2; ++mt)
        #pragma unroll
        for (int i = 0; i < 4; ++i)
          glp[kq][mt * 16 + r4 + i][ccol] = acc[mt][i];
      __syncthreads();

      if (tid < 256) {
        float g4[4][2];
        #pragma unroll
        for (int gg = 0; gg < 4; ++gg) {
          g4[gg][0] = glp[0][cb][gg * 16 + cd] + glp[1][cb][gg * 16 + cd]
                    + glp[2][cb][gg * 16 + cd] + glp[3][cb][gg * 16 + cd];
          g4[gg][1] = glp[0][cb][gg * 16 + cd + 1] + glp[1][cb][gg * 16 + cd + 1]
                    + glp[2][cb][gg * 16 + cd + 1] + glp[3][cb][gg * 16 + cd + 1];
        }
        const float i0 = 1.f / (1.f + expf(-g4[0][0])), i1 = 1.f / (1.f + expf(-g4[0][1]));
        const float f0 = 1.f / (1.f + expf(-g4[1][0])), f1 = 1.f / (1.f + expf(-g4[1][1]));
        const float z0 = tanhf(g4[2][0]),               z1 = tanhf(g4[2][1]);
        const float o0 = 1.f / (1.f + expf(-g4[3][0])), o1 = 1.f / (1.f + expf(-g4[3][1]));
        creg0 = f0 * creg0 + i0 * z0;
        creg1 = f1 * creg1 + i1 * z1;
        const float hn0 = o0 * tanhf(creg0);
        const float hn1 = o1 * tanhf(creg1);
        union { u16 us[2]; u32 u; } pk;
        pk.us[0] = h2u((_Float16)hn0);
        pk.us[1] = h2u((_Float16)hn1);
        _Float16* hw = lyr ? (h1 + (size_t)pp * HS) : (h0 + (size_t)cc * HS);
        cohs32((u32*)(hw + (size_t)(mbase + cb) * D_ + d0 + cd), pk.u);
        if (lyr) {
          float2 o2; o2.x = hn0; o2.y = hn1;
          *(float2*)(out + ((size_t)(mbase + cb) * T_ + t) * D_ + d0 + cd) = o2;
        }
      }
    }

    // single grid barrier (relaxed atomics only -> no cache maintenance).
    // __syncthreads drains each wave's vmcnt before s_barrier, so all h
    // stores are at the coherence point before tid0 arrives.
    __syncthreads();
    if (tid == 0) {
      __hip_atomic_fetch_add(bar, 1u, __ATOMIC_RELAXED, __HIP_MEMORY_SCOPE_AGENT);
      const u32 tgt = (u32)(s + 1) * NBLK;
      while (__hip_atomic_load(bar, __ATOMIC_RELAXED, __HIP_MEMORY_SCOPE_AGENT) < tgt)
        __builtin_amdgcn_s_sleep(2);
    }
    __syncthreads();
  }
}

// ---- setup ---------------------------------------------------------------

__global__ void convw(const float* __restrict__ w0, const float* __restrict__ w1,
                      const float* __restrict__ w2, const float* __restrict__ w3,
                      u64* __restrict__ dst) {
  const size_t n1 = (size_t)D_ * D_;          // float4 count per matrix
  const size_t n = 4 * n1;
  for (size_t i = (size_t)blockIdx.x * blockDim.x + threadIdx.x; i < n;
       i += (size_t)gridDim.x * blockDim.x) {
    const size_t m = i / n1, j = i - m * n1;
    const float* src = (m == 0) ? w0 : (m == 1) ? w1 : (m == 2) ? w2 : w3;
    float4 v = ((const float4*)src)[j];
    union { u16 us[4]; u64 u; } pk;
    pk.us[0] = h2u((_Float16)v.x); pk.us[1] = h2u((_Float16)v.y);
    pk.us[2] = h2u((_Float16)v.z); pk.us[3] = h2u((_Float16)v.w);
    dst[i] = pk.u;
  }
}

__global__ void convx(const float* __restrict__ x, u64* __restrict__ xh) {
  const size_t n = (size_t)B_ * T_ * D_ / 4;
  for (size_t i = (size_t)blockIdx.x * blockDim.x + threadIdx.x; i < n;
       i += (size_t)gridDim.x * blockDim.x) {
    float4 v = ((const float4*)x)[i];
    union { u16 us[4]; u64 u; } pk;
    pk.us[0] = h2u((_Float16)v.x); pk.us[1] = h2u((_Float16)v.y);
    pk.us[2] = h2u((_Float16)v.z); pk.us[3] = h2u((_Float16)v.w);
    xh[i] = pk.u;
  }
}

// ---- host ----------------------------------------------------------------

extern "C" void kernel_launch(void* const* d_in, const int* in_sizes, int n_in,
                              void* d_out, int out_size, void* d_ws, size_t ws_size,
                              hipStream_t stream) {
  (void)in_sizes; (void)n_in; (void)out_size;
  const float* x = (const float*)d_in[0];
  const float* Wih0 = (const float*)d_in[1];
  const float* Whh0 = (const float*)d_in[2];
  const float* Wih1 = (const float*)d_in[3];
  const float* Whh1 = (const float*)d_in[4];
  float* out = (float*)d_out;

  char* ws = (char*)d_ws;
  const size_t MB = 1ull << 20;
  // layout: [0,32MB) W fp16; 32MB: h0[2] 256KB, h1[2] 256KB, bar 4KB; 33MB: xh 128MB
  _Float16* Wf = (_Float16*)ws;
  _Float16* h0 = (_Float16*)(ws + 32 * MB);
  _Float16* h1 = (_Float16*)(ws + 32 * MB + 262144);
  u32* bar = (u32*)(ws + 32 * MB + 2 * 262144);
  _Float16* xh = (_Float16*)(ws + 33 * MB);
  const bool xpre = ws_size >= 33 * MB + (size_t)B_ * T_ * D_ * 2;

  hipMemsetAsync(ws + 32 * MB, 0, 2 * 262144 + 4096, stream);
  convw<<<4096, 256, 0, stream>>>(Wih0, Whh0, Wih1, Whh1, (u64*)Wf);
  if (xpre) {
    convx<<<4096, 256, 0, stream>>>(x, (u64*)xh);
    lstm_persist<true><<<NBLK, 1024, 0, stream>>>(x, xh, Wf, h0, h1, out, bar);
  } else {
    lstm_persist<false><<<NBLK, 1024, 0, stream>>>(x, xh, Wf, h0, h1, out, bar);
  }
}

// Round 5
// 9220.982 us; speedup vs baseline: 12.7214x; 2.9147x over previous
//
#include <hip/hip_runtime.h>
#include <cstdint>
#include <cstddef>

#define B_ 64
#define T_ 1024
#define D_ 1024
#define NBLK 256

typedef __attribute__((ext_vector_type(8))) _Float16 half8;
typedef __attribute__((ext_vector_type(4))) float f32x4;
typedef unsigned int u32;
typedef unsigned long long u64;
typedef unsigned short u16;

static __device__ __forceinline__ f32x4 mfma16(half8 a, half8 b, f32x4 c) {
  return __builtin_amdgcn_mfma_f32_16x16x32_f16(a, b, c, 0, 0, 0);
}
static __device__ __forceinline__ u64 cohl64(const u64* p) {
  return __hip_atomic_load(p, __ATOMIC_RELAXED, __HIP_MEMORY_SCOPE_AGENT);
}
static __device__ __forceinline__ u32 cohl32(const u32* p) {
  return __hip_atomic_load(p, __ATOMIC_RELAXED, __HIP_MEMORY_SCOPE_AGENT);
}
static __device__ __forceinline__ void cohs32(u32* p, u32 v) {
  __hip_atomic_store(p, v, __ATOMIC_RELAXED, __HIP_MEMORY_SCOPE_AGENT);
}
static __device__ __forceinline__ u16 h2u(_Float16 h) {
  return __builtin_bit_cast(u16, h);
}

// ---- staging: 32 rows x 1024 fp16 (2048B/row) -> LDS, XOR-swizzled -------
// thread t: row r=t>>5, lane j=t&31; covers bytes j*16 + k*512 (k=0..3).
// Write: consecutive lanes -> consecutive (swizzle-permuted) 16B slots ->
// conflict-free ds_write_b128 (old layout was 64B-stride = 16-way conflict).

static __device__ __forceinline__ void stage_coh(const _Float16* src, u64* st, int tid) {
  const int r = tid >> 5, j = tid & 31;
  const u64* p = (const u64*)(src + (size_t)r * D_) + j * 2;
  #pragma unroll
  for (int k = 0; k < 4; ++k) {
    st[2 * k] = cohl64(p + k * 64);
    st[2 * k + 1] = cohl64(p + k * 64 + 1);
  }
}

static __device__ __forceinline__ void stage_x(const _Float16* src, u64* st, int tid) {
  const int r = tid >> 5, j = tid & 31;
  const u64* p = (const u64*)(src + (size_t)r * T_ * D_) + j * 2;
  #pragma unroll
  for (int k = 0; k < 4; ++k) {
    st[2 * k] = p[k * 64];
    st[2 * k + 1] = p[k * 64 + 1];
  }
}

static __device__ __forceinline__ void stage_xf(const float* src, u64* st, int tid) {
  const int r = tid >> 5, j = tid & 31;
  const float4* p = (const float4*)(src + (size_t)r * T_ * D_) + j * 2;
  #pragma unroll
  for (int k = 0; k < 4; ++k) {
    #pragma unroll
    for (int q = 0; q < 2; ++q) {
      float4 v = p[k * 64 + q];
      union { u16 us[4]; u64 u; } pk;
      pk.us[0] = h2u((_Float16)v.x); pk.us[1] = h2u((_Float16)v.y);
      pk.us[2] = h2u((_Float16)v.z); pk.us[3] = h2u((_Float16)v.w);
      st[2 * k + q] = pk.u;
    }
  }
}

static __device__ __forceinline__ void stage_write(char* lds, const u64* st, int tid) {
  const int r = tid >> 5, j = tid & 31;
  const int sw = (r & 7) << 4;
  char* row = lds + r * 2048;
  #pragma unroll
  for (int k = 0; k < 4; ++k) {
    char* dst = row + ((j * 16 + k * 512) ^ sw);
    *(u64*)dst = st[2 * k];
    *(u64*)(dst + 8) = st[2 * k + 1];
  }
}

// ---- GEMM: weights from REGISTERS (preloaded once for all 1024 steps) ----
static __device__ __forceinline__ void gemm_reg(
    f32x4* acc, const char* ldsA, const half8* w, int kq, int lane) {
  const int r = lane & 15;
  const int kl2 = (lane >> 4) << 4;
  const int sw = (r & 7) << 4;
  const char* p0 = ldsA + r * 2048;
  const char* p1 = ldsA + (16 + r) * 2048;   // (16+r)&7 == r&7 -> same swizzle
  #pragma unroll
  for (int ks = 0; ks < 8; ++ks) {
    const int kb = (kq * 512 + ks * 64 + kl2) ^ sw;
    half8 a0 = *(const half8*)(p0 + kb);
    half8 a1 = *(const half8*)(p1 + kb);
    acc[0] = mfma16(a0, w[ks], acc[0]);
    acc[1] = mfma16(a1, w[ks], acc[1]);
  }
}

// ---- persistent kernel ---------------------------------------------------
// 256 blocks x 1024 threads. xcd=bid&7, slot=bid>>3:
//   lyr=slot>>4, mh=(slot>>3)&1, dgrp=xcd*8+(slot&7).
// Block: layer lyr, batch rows mbase..+32, dims d0..+16 (4 gates), K=1024.
// 16 waves = (kq 0..3)x(gate 0..3); wave: 2 m-tiles, weights in 64 VGPRs.
// Super-step s: lyr0 does t=s, lyr1 does t=s-1. One scatter/gather barrier.

template <bool XPRE>
__global__ __launch_bounds__(1024, 4) void lstm_persist(
    const float* __restrict__ x32, const _Float16* __restrict__ xh,
    const _Float16* __restrict__ W,
    _Float16* h0, _Float16* h1,    // [2 parity][B][D] each
    float* __restrict__ out, u32* slots, u32* go)
{
  __shared__ char ldsA[32 * 2048];
  __shared__ float glp[4][32][68];
  const int tid = threadIdx.x;
  const int lane = tid & 63;
  const int wv = tid >> 6;
  const int kq = wv >> 2;
  const int nt = wv & 3;                   // gate (i,f,g,o)
  const int bid = blockIdx.x;
  const int slot = bid >> 3;
  const int lyr = slot >> 4;
  const int mh = (slot >> 3) & 1;
  const int dgrp = (bid & 7) * 8 + (slot & 7);
  const int d0 = dgrp << 4;
  const int mbase = mh << 5;

  // ---- weight preload: 8+8 half8 fragments per lane (64 VGPR) ----
  const _Float16* Wih = W + (size_t)(2 * lyr) * 4096 * 1024;
  const _Float16* Whh = Wih + (size_t)4096 * 1024;
  const size_t wrow = (size_t)(nt * 1024 + d0 + (lane & 15)) * 1024;
  const int kl2 = (lane >> 4) << 4;
  half8 wih[8], whh[8];
  #pragma unroll
  for (int ks = 0; ks < 8; ++ks) {
    const int kb = kq * 512 + ks * 64 + kl2;       // byte offset in row
    wih[ks] = *(const half8*)(Wih + wrow + (kb >> 1));
    whh[ks] = *(const half8*)(Whh + wrow + (kb >> 1));
  }

  float creg0 = 0.f, creg1 = 0.f;       // cell state lives in registers
  const int cb = tid >> 3;
  const int cd = (tid & 7) << 1;
  const size_t HS = (size_t)B_ * D_;

  u64 st[8];
  if (lyr == 0) {                        // prefetch x for s=0
    if (XPRE) stage_x(xh + (size_t)mbase * T_ * D_, st, tid);
    else      stage_xf(x32 + (size_t)mbase * T_ * D_, st, tid);
  }

  for (int s = 0; s <= T_; ++s) {
    const bool active = lyr ? (s >= 1) : (s < T_);
    const int t = lyr ? (s - 1) : s;
    const int pp = (s + 1) & 1, cc = s & 1;

    if (active) {
      const _Float16* h0prev = h0 + (size_t)pp * HS + (size_t)mbase * D_;
      // operand 1: lyr0 = x (prefetched in st), lyr1 = h0[t]
      if (lyr == 1) stage_coh(h0prev, st, tid);
      stage_write(ldsA, st, tid);
      __syncthreads();
      // issue recurrent-h load now; overlaps gemm1
      if (lyr == 0) stage_coh(h0prev, st, tid);
      else          stage_coh(h1 + (size_t)cc * HS + (size_t)mbase * D_, st, tid);

      f32x4 acc[2];
      acc[0] = (f32x4){0.f, 0.f, 0.f, 0.f};
      acc[1] = (f32x4){0.f, 0.f, 0.f, 0.f};
      gemm_reg(acc, ldsA, wih, kq, lane);
      __syncthreads();
      stage_write(ldsA, st, tid);
      __syncthreads();
      gemm_reg(acc, ldsA, whh, kq, lane);

      // kq partials -> LDS
      const int r4 = (lane >> 4) << 2;
      const int ccol = nt * 16 + (lane & 15);
      #pragma unroll
      for (int mt = 0; mt < 2; ++mt)
        #pragma unroll
        for (int i = 0; i < 4; ++i)
          glp[kq][mt * 16 + r4 + i][ccol] = acc[mt][i];
      __syncthreads();

      if (tid < 256) {
        float g4[4][2];
        #pragma unroll
        for (int gg = 0; gg < 4; ++gg) {
          g4[gg][0] = glp[0][cb][gg * 16 + cd] + glp[1][cb][gg * 16 + cd]
                    + glp[2][cb][gg * 16 + cd] + glp[3][cb][gg * 16 + cd];
          g4[gg][1] = glp[0][cb][gg * 16 + cd + 1] + glp[1][cb][gg * 16 + cd + 1]
                    + glp[2][cb][gg * 16 + cd + 1] + glp[3][cb][gg * 16 + cd + 1];
        }
        const float i0 = 1.f / (1.f + expf(-g4[0][0])), i1 = 1.f / (1.f + expf(-g4[0][1]));
        const float f0 = 1.f / (1.f + expf(-g4[1][0])), f1 = 1.f / (1.f + expf(-g4[1][1]));
        const float z0 = tanhf(g4[2][0]),               z1 = tanhf(g4[2][1]);
        const float o0 = 1.f / (1.f + expf(-g4[3][0])), o1 = 1.f / (1.f + expf(-g4[3][1]));
        creg0 = f0 * creg0 + i0 * z0;
        creg1 = f1 * creg1 + i1 * z1;
        const float hn0 = o0 * tanhf(creg0);
        const float hn1 = o1 * tanhf(creg1);
        union { u16 us[2]; u32 u; } pk;
        pk.us[0] = h2u((_Float16)hn0);
        pk.us[1] = h2u((_Float16)hn1);
        _Float16* hw = lyr ? (h1 + (size_t)pp * HS) : (h0 + (size_t)cc * HS);
        cohs32((u32*)(hw + (size_t)(mbase + cb) * D_ + d0 + cd), pk.u);
        if (lyr) {
          float2 o2; o2.x = hn0; o2.y = hn1;
          *(float2*)(out + ((size_t)(mbase + cb) * T_ + t) * D_ + d0 + cd) = o2;
        }
      }

      // prefetch next x (hides under barrier wait; completes by vmcnt drain)
      if (lyr == 0 && s + 1 < T_) {
        if (XPRE) stage_x(xh + (size_t)mbase * T_ * D_ + (size_t)(s + 1) * D_, st, tid);
        else      stage_xf(x32 + (size_t)mbase * T_ * D_ + (size_t)(s + 1) * D_, st, tid);
      }
    }

    // ---- scatter/gather grid barrier (no contended atomics) ----
    // syncthreads drains vmcnt(0) per wave -> h stores + prefetch complete
    __syncthreads();
    const u32 gen = (u32)(s + 1);
    if (tid == 0) cohs32(slots + bid * 32, gen);
    if (bid == 0) {
      if (tid < NBLK)
        while (cohl32(slots + tid * 32) < gen) __builtin_amdgcn_s_sleep(4);
      __syncthreads();
      if (tid == 0) cohs32(go, gen);
    } else {
      if (tid == 0)
        while (cohl32(go) < gen) __builtin_amdgcn_s_sleep(4);
      __syncthreads();
    }
  }
}

// ---- setup ---------------------------------------------------------------

__global__ void convw(const float* __restrict__ w0, const float* __restrict__ w1,
                      const float* __restrict__ w2, const float* __restrict__ w3,
                      u64* __restrict__ dst) {
  const size_t n1 = (size_t)D_ * D_;          // float4 count per matrix
  const size_t n = 4 * n1;
  for (size_t i = (size_t)blockIdx.x * blockDim.x + threadIdx.x; i < n;
       i += (size_t)gridDim.x * blockDim.x) {
    const size_t m = i / n1, j = i - m * n1;
    const float* src = (m == 0) ? w0 : (m == 1) ? w1 : (m == 2) ? w2 : w3;
    float4 v = ((const float4*)src)[j];
    union { u16 us[4]; u64 u; } pk;
    pk.us[0] = h2u((_Float16)v.x); pk.us[1] = h2u((_Float16)v.y);
    pk.us[2] = h2u((_Float16)v.z); pk.us[3] = h2u((_Float16)v.w);
    dst[i] = pk.u;
  }
}

__global__ void convx(const float* __restrict__ x, u64* __restrict__ xh) {
  const size_t n = (size_t)B_ * T_ * D_ / 4;
  for (size_t i = (size_t)blockIdx.x * blockDim.x + threadIdx.x; i < n;
       i += (size_t)gridDim.x * blockDim.x) {
    float4 v = ((const float4*)x)[i];
    union { u16 us[4]; u64 u; } pk;
    pk.us[0] = h2u((_Float16)v.x); pk.us[1] = h2u((_Float16)v.y);
    pk.us[2] = h2u((_Float16)v.z); pk.us[3] = h2u((_Float16)v.w);
    xh[i] = pk.u;
  }
}

// ---- host ----------------------------------------------------------------

extern "C" void kernel_launch(void* const* d_in, const int* in_sizes, int n_in,
                              void* d_out, int out_size, void* d_ws, size_t ws_size,
                              hipStream_t stream) {
  (void)in_sizes; (void)n_in; (void)out_size;
  const float* x = (const float*)d_in[0];
  const float* Wih0 = (const float*)d_in[1];
  const float* Whh0 = (const float*)d_in[2];
  const float* Wih1 = (const float*)d_in[3];
  const float* Whh1 = (const float*)d_in[4];
  float* out = (float*)d_out;

  char* ws = (char*)d_ws;
  const size_t MB = 1ull << 20;
  // layout: [0,32MB) W fp16; 32MB: h0[2] 256KB, h1[2] 256KB, slots 32KB,
  //         go 128B; 33MB: xh 128MB
  _Float16* Wf = (_Float16*)ws;
  _Float16* h0 = (_Float16*)(ws + 32 * MB);
  _Float16* h1 = (_Float16*)(ws + 32 * MB + 262144);
  u32* slots = (u32*)(ws + 32 * MB + 2 * 262144);
  u32* go = (u32*)(ws + 32 * MB + 2 * 262144 + 32768);
  _Float16* xh = (_Float16*)(ws + 33 * MB);
  const bool xpre = ws_size >= 33 * MB + (size_t)B_ * T_ * D_ * 2;

  hipMemsetAsync(ws + 32 * MB, 0, 2 * 262144 + 32768 + 128, stream);
  convw<<<4096, 256, 0, stream>>>(Wih0, Whh0, Wih1, Whh1, (u64*)Wf);
  if (xpre) {
    convx<<<4096, 256, 0, stream>>>(x, (u64*)xh);
    lstm_persist<true><<<NBLK, 1024, 0, stream>>>(x, xh, Wf, h0, h1, out, slots, go);
  } else {
    lstm_persist<false><<<NBLK, 1024, 0, stream>>>(x, xh, Wf, h0, h1, out, slots, go);
  }
}

// Round 6
// 8701.624 us; speedup vs baseline: 13.4807x; 1.0597x over previous
//
#include <hip/hip_runtime.h>
#include <cstdint>
#include <cstddef>

#define B_ 64
#define T_ 1024
#define D_ 1024
#define NBLK 256

typedef __attribute__((ext_vector_type(8))) _Float16 half8;
typedef __attribute__((ext_vector_type(4))) float f32x4;
typedef unsigned int u32;
typedef unsigned long long u64;
typedef unsigned short u16;

static __device__ __forceinline__ f32x4 mfma16(half8 a, half8 b, f32x4 c) {
  return __builtin_amdgcn_mfma_f32_16x16x32_f16(a, b, c, 0, 0, 0);
}
static __device__ __forceinline__ u64 cohl64(const u64* p) {
  return __hip_atomic_load(p, __ATOMIC_RELAXED, __HIP_MEMORY_SCOPE_AGENT);
}
static __device__ __forceinline__ u32 cohl32(const u32* p) {
  return __hip_atomic_load(p, __ATOMIC_RELAXED, __HIP_MEMORY_SCOPE_AGENT);
}
static __device__ __forceinline__ void cohs32(u32* p, u32 v) {
  __hip_atomic_store(p, v, __ATOMIC_RELAXED, __HIP_MEMORY_SCOPE_AGENT);
}
static __device__ __forceinline__ u16 h2u(_Float16 h) {
  return __builtin_bit_cast(u16, h);
}

// ---- staging: 32 rows x 1024 fp16 (2048B/row) -> LDS, XOR-swizzled -------
// thread t: row r=t>>5, lane j=t&31; covers bytes j*16 + k*512 (k=0..3).

static __device__ __forceinline__ void stage_coh(const _Float16* src, u64* st, int tid) {
  const int r = tid >> 5, j = tid & 31;
  const u64* p = (const u64*)(src + (size_t)r * D_) + j * 2;
  #pragma unroll
  for (int k = 0; k < 4; ++k) {
    st[2 * k] = cohl64(p + k * 64);
    st[2 * k + 1] = cohl64(p + k * 64 + 1);
  }
}

static __device__ __forceinline__ void stage_x(const _Float16* src, u64* st, int tid) {
  const int r = tid >> 5, j = tid & 31;
  const u64* p = (const u64*)(src + (size_t)r * T_ * D_) + j * 2;
  #pragma unroll
  for (int k = 0; k < 4; ++k) {
    st[2 * k] = p[k * 64];
    st[2 * k + 1] = p[k * 64 + 1];
  }
}

static __device__ __forceinline__ void stage_xf(const float* src, u64* st, int tid) {
  const int r = tid >> 5, j = tid & 31;
  const float4* p = (const float4*)(src + (size_t)r * T_ * D_) + j * 2;
  #pragma unroll
  for (int k = 0; k < 4; ++k) {
    #pragma unroll
    for (int q = 0; q < 2; ++q) {
      float4 v = p[k * 64 + q];
      union { u16 us[4]; u64 u; } pk;
      pk.us[0] = h2u((_Float16)v.x); pk.us[1] = h2u((_Float16)v.y);
      pk.us[2] = h2u((_Float16)v.z); pk.us[3] = h2u((_Float16)v.w);
      st[2 * k + q] = pk.u;
    }
  }
}

static __device__ __forceinline__ void stage_write(char* lds, const u64* st, int tid) {
  const int r = tid >> 5, j = tid & 31;
  const int sw = (r & 7) << 4;
  char* row = lds + r * 2048;
  #pragma unroll
  for (int k = 0; k < 4; ++k) {
    char* dst = row + ((j * 16 + k * 512) ^ sw);
    *(u64*)dst = st[2 * k];
    *(u64*)(dst + 8) = st[2 * k + 1];
  }
}

// ---- GEMM: weights from REGISTERS (preloaded, pinned via opaque asm) -----
static __device__ __forceinline__ void gemm_reg(
    f32x4* acc, const char* ldsA, const half8* w, int kq, int lane) {
  const int r = lane & 15;
  const int kl2 = (lane >> 4) << 4;
  const int sw = (r & 7) << 4;
  const char* p0 = ldsA + r * 2048;
  const char* p1 = ldsA + (16 + r) * 2048;   // (16+r)&7 == r&7 -> same swizzle
  #pragma unroll
  for (int ks = 0; ks < 8; ++ks) {
    const int kb = (kq * 512 + ks * 64 + kl2) ^ sw;
    half8 a0 = *(const half8*)(p0 + kb);
    half8 a1 = *(const half8*)(p1 + kb);
    acc[0] = mfma16(a0, w[ks], acc[0]);
    acc[1] = mfma16(a1, w[ks], acc[1]);
  }
}

// ---- persistent kernel ---------------------------------------------------
// 256 blocks x 1024 threads. xcd=bid&7, slot=bid>>3:
//   lyr=slot>>4, mh=(slot>>3)&1, dgrp=xcd*8+(slot&7).
// Block: layer lyr, batch rows mbase..+32, dims d0..+16 (4 gates), K=1024.
// 16 waves = (kq 0..3)x(gate 0..3); wave: 2 m-tiles, weights in 64 VGPRs.
// Super-step s: lyr0 does t=s, lyr1 does t=s-1. All-to-all 1-hop barrier.

template <bool XPRE>
__global__ __launch_bounds__(1024, 4) void lstm_persist(
    const float* __restrict__ x32, const _Float16* __restrict__ xh,
    const _Float16* __restrict__ W,
    _Float16* h0, _Float16* h1,    // [2 parity][B][D] each
    float* __restrict__ out, u32* slots)
{
  __shared__ char ldsA[32 * 2048];
  __shared__ float glp[4][32][68];
  const int tid = threadIdx.x;
  const int lane = tid & 63;
  const int wv = tid >> 6;
  const int kq = wv >> 2;
  const int nt = wv & 3;                   // gate (i,f,g,o)
  const int bid = blockIdx.x;
  const int slot = bid >> 3;
  const int lyr = slot >> 4;
  const int mh = (slot >> 3) & 1;
  const int dgrp = (bid & 7) * 8 + (slot & 7);
  const int d0 = dgrp << 4;
  const int mbase = mh << 5;

  // ---- weight preload: 8+8 half8 fragments per lane (64 VGPR) ----
  const _Float16* Wih = W + (size_t)(2 * lyr) * 4096 * 1024;
  const _Float16* Whh = Wih + (size_t)4096 * 1024;
  const size_t wrow = (size_t)(nt * 1024 + d0 + (lane & 15)) * 1024;
  const int kl2 = (lane >> 4) << 4;
  half8 wih[8], whh[8];
  #pragma unroll
  for (int ks = 0; ks < 8; ++ks) {
    const int kb = kq * 512 + ks * 64 + kl2;       // byte offset in row
    wih[ks] = *(const half8*)(Wih + wrow + (kb >> 1));
    whh[ks] = *(const half8*)(Whh + wrow + (kb >> 1));
  }
  // Opaque pass-through: values become asm outputs -> compiler cannot
  // rematerialize them from memory inside the loop; they must stay in VGPRs.
  #pragma unroll
  for (int ks = 0; ks < 8; ++ks) {
    asm volatile("" : "+v"(wih[ks]));
    asm volatile("" : "+v"(whh[ks]));
  }

  float creg0 = 0.f, creg1 = 0.f;       // cell state lives in registers
  const int cb = tid >> 3;
  const int cd = (tid & 7) << 1;
  const size_t HS = (size_t)B_ * D_;

  u64 st[8];
  if (lyr == 0) {                        // prefetch x for s=0
    if (XPRE) stage_x(xh + (size_t)mbase * T_ * D_, st, tid);
    else      stage_xf(x32 + (size_t)mbase * T_ * D_, st, tid);
  }

  for (int s = 0; s <= T_; ++s) {
    const bool active = lyr ? (s >= 1) : (s < T_);
    const int t = lyr ? (s - 1) : s;
    const int pp = (s + 1) & 1, cc = s & 1;

    if (active) {
      const _Float16* h0prev = h0 + (size_t)pp * HS + (size_t)mbase * D_;
      // operand 1: lyr0 = x (prefetched in st), lyr1 = h0[t]
      if (lyr == 1) stage_coh(h0prev, st, tid);
      stage_write(ldsA, st, tid);
      __syncthreads();
      // issue recurrent-h load now; overlaps gemm1
      if (lyr == 0) stage_coh(h0prev, st, tid);
      else          stage_coh(h1 + (size_t)cc * HS + (size_t)mbase * D_, st, tid);

      f32x4 acc[2];
      acc[0] = (f32x4){0.f, 0.f, 0.f, 0.f};
      acc[1] = (f32x4){0.f, 0.f, 0.f, 0.f};
      gemm_reg(acc, ldsA, wih, kq, lane);
      __syncthreads();
      stage_write(ldsA, st, tid);
      __syncthreads();
      gemm_reg(acc, ldsA, whh, kq, lane);

      // kq partials -> LDS
      const int r4 = (lane >> 4) << 2;
      const int ccol = nt * 16 + (lane & 15);
      #pragma unroll
      for (int mt = 0; mt < 2; ++mt)
        #pragma unroll
        for (int i = 0; i < 4; ++i)
          glp[kq][mt * 16 + r4 + i][ccol] = acc[mt][i];
      __syncthreads();

      if (tid < 256) {
        float g4[4][2];
        #pragma unroll
        for (int gg = 0; gg < 4; ++gg) {
          g4[gg][0] = glp[0][cb][gg * 16 + cd] + glp[1][cb][gg * 16 + cd]
                    + glp[2][cb][gg * 16 + cd] + glp[3][cb][gg * 16 + cd];
          g4[gg][1] = glp[0][cb][gg * 16 + cd + 1] + glp[1][cb][gg * 16 + cd + 1]
                    + glp[2][cb][gg * 16 + cd + 1] + glp[3][cb][gg * 16 + cd + 1];
        }
        const float i0 = 1.f / (1.f + expf(-g4[0][0])), i1 = 1.f / (1.f + expf(-g4[0][1]));
        const float f0 = 1.f / (1.f + expf(-g4[1][0])), f1 = 1.f / (1.f + expf(-g4[1][1]));
        const float z0 = tanhf(g4[2][0]),               z1 = tanhf(g4[2][1]);
        const float o0 = 1.f / (1.f + expf(-g4[3][0])), o1 = 1.f / (1.f + expf(-g4[3][1]));
        creg0 = f0 * creg0 + i0 * z0;
        creg1 = f1 * creg1 + i1 * z1;
        const float hn0 = o0 * tanhf(creg0);
        const float hn1 = o1 * tanhf(creg1);
        union { u16 us[2]; u32 u; } pk;
        pk.us[0] = h2u((_Float16)hn0);
        pk.us[1] = h2u((_Float16)hn1);
        _Float16* hw = lyr ? (h1 + (size_t)pp * HS) : (h0 + (size_t)cc * HS);
        cohs32((u32*)(hw + (size_t)(mbase + cb) * D_ + d0 + cd), pk.u);
        if (lyr) {
          float2 o2; o2.x = hn0; o2.y = hn1;
          *(float2*)(out + ((size_t)(mbase + cb) * T_ + t) * D_ + d0 + cd) = o2;
        }
      }

      // prefetch next x (hides under barrier wait; completes by vmcnt drain)
      if (lyr == 0 && s + 1 < T_) {
        if (XPRE) stage_x(xh + (size_t)mbase * T_ * D_ + (size_t)(s + 1) * D_, st, tid);
        else      stage_xf(x32 + (size_t)mbase * T_ * D_ + (size_t)(s + 1) * D_, st, tid);
      }
    }

    // ---- all-to-all 1-hop grid barrier ----
    // syncthreads drains vmcnt(0) per wave -> h stores + prefetch complete
    __syncthreads();
    const u32 gen = (u32)(s + 1);
    if (tid == 0) cohs32(slots + bid * 32, gen);
    if (tid < NBLK)
      while (cohl32(slots + tid * 32) < gen) __builtin_amdgcn_s_sleep(2);
    __syncthreads();
  }
}

// ---- setup ---------------------------------------------------------------

__global__ void convw(const float* __restrict__ w0, const float* __restrict__ w1,
                      const float* __restrict__ w2, const float* __restrict__ w3,
                      u64* __restrict__ dst) {
  const size_t n1 = (size_t)D_ * D_;          // float4 count per matrix
  const size_t n = 4 * n1;
  for (size_t i = (size_t)blockIdx.x * blockDim.x + threadIdx.x; i < n;
       i += (size_t)gridDim.x * blockDim.x) {
    const size_t m = i / n1, j = i - m * n1;
    const float* src = (m == 0) ? w0 : (m == 1) ? w1 : (m == 2) ? w2 : w3;
    float4 v = ((const float4*)src)[j];
    union { u16 us[4]; u64 u; } pk;
    pk.us[0] = h2u((_Float16)v.x); pk.us[1] = h2u((_Float16)v.y);
    pk.us[2] = h2u((_Float16)v.z); pk.us[3] = h2u((_Float16)v.w);
    dst[i] = pk.u;
  }
}

__global__ void convx(const float* __restrict__ x, u64* __restrict__ xh) {
  const size_t n = (size_t)B_ * T_ * D_ / 4;
  for (size_t i = (size_t)blockIdx.x * blockDim.x + threadIdx.x; i < n;
       i += (size_t)gridDim.x * blockDim.x) {
    float4 v = ((const float4*)x)[i];
    union { u16 us[4]; u64 u; } pk;
    pk.us[0] = h2u((_Float16)v.x); pk.us[1] = h2u((_Float16)v.y);
    pk.us[2] = h2u((_Float16)v.z); pk.us[3] = h2u((_Float16)v.w);
    xh[i] = pk.u;
  }
}

// ---- host ----------------------------------------------------------------

extern "C" void kernel_launch(void* const* d_in, const int* in_sizes, int n_in,
                              void* d_out, int out_size, void* d_ws, size_t ws_size,
                              hipStream_t stream) {
  (void)in_sizes; (void)n_in; (void)out_size;
  const float* x = (const float*)d_in[0];
  const float* Wih0 = (const float*)d_in[1];
  const float* Whh0 = (const float*)d_in[2];
  const float* Wih1 = (const float*)d_in[3];
  const float* Whh1 = (const float*)d_in[4];
  float* out = (float*)d_out;

  char* ws = (char*)d_ws;
  const size_t MB = 1ull << 20;
  // layout: [0,32MB) W fp16; 32MB: h0[2] 256KB, h1[2] 256KB, slots 32KB;
  //         33MB: xh 128MB
  _Float16* Wf = (_Float16*)ws;
  _Float16* h0 = (_Float16*)(ws + 32 * MB);
  _Float16* h1 = (_Float16*)(ws + 32 * MB + 262144);
  u32* slots = (u32*)(ws + 32 * MB + 2 * 262144);
  _Float16* xh = (_Float16*)(ws + 33 * MB);
  const bool xpre = ws_size >= 33 * MB + (size_t)B_ * T_ * D_ * 2;

  hipMemsetAsync(ws + 32 * MB, 0, 2 * 262144 + 32768, stream);
  convw<<<4096, 256, 0, stream>>>(Wih0, Whh0, Wih1, Whh1, (u64*)Wf);
  if (xpre) {
    convx<<<4096, 256, 0, stream>>>(x, (u64*)xh);
    lstm_persist<true><<<NBLK, 1024, 0, stream>>>(x, xh, Wf, h0, h1, out, slots);
  } else {
    lstm_persist<false><<<NBLK, 1024, 0, stream>>>(x, xh, Wf, h0, h1, out, slots);
  }
}